// Round 9
// baseline (776.131 us; speedup 1.0000x reference)
//
#include <hip/hip_runtime.h>

// Transposed flash attention, f16 MFMA (16x16x32), no-max softmax, split-K=N.
// S^T = K*Q^T and O^T = V^T*P^T; P stays in registers (in-lane repack), no sP.
// LDS = sK+sV = 16 KB/block -> 4 blocks/CU at VGPR=128.
// Split-K chosen from ws_size: 4 (needs ~51.4 MB ws) else 2 (~17 MB, proven).
// Partials: half 0 -> d_out, half p>0 -> ws+(p-1)*OELEMS; row-sums after them.

#define NBATCH 16
#define SEQ    4096
#define DIM    64
#define BQ     256
#define BK     64
#define NKT    (SEQ / BK)
#define OELEMS (NBATCH * SEQ * DIM)
#define NROWS  (NBATCH * SEQ)

#define QSCALE 0.180336879f   // 0.125 * log2(e)

typedef _Float16 half2_t __attribute__((ext_vector_type(2)));
typedef _Float16 half4_t __attribute__((ext_vector_type(4)));
typedef _Float16 half8_t __attribute__((ext_vector_type(8)));
typedef float    floatx4 __attribute__((ext_vector_type(4)));

__device__ inline float fast_exp2(float x) {
#if __has_builtin(__builtin_amdgcn_exp2f)
  return __builtin_amdgcn_exp2f(x);
#else
  return exp2f(x);
#endif
}
__device__ inline float fast_rcp(float x) {
#if __has_builtin(__builtin_amdgcn_rcpf)
  return __builtin_amdgcn_rcpf(x);
#else
  return 1.0f / x;
#endif
}

// swizzled offset in halfs for element (row, col) of a 64x64 half tile
__device__ inline int swz(int row, int col) {
  return row * 64 + ((((col >> 3) ^ ((row >> 1) & 7)) << 3) | (col & 7));
}

__global__ __launch_bounds__(256, 4)
void attn_f16_flash(const float* __restrict__ Qg, const float* __restrict__ Kg,
                    const float* __restrict__ Vg, float* __restrict__ O0g,
                    float* __restrict__ Opg, float* __restrict__ lsg,
                    int ksh, int ksteps)
{
  __shared__ __align__(16) _Float16 sK[64 * 64];   // [key][dim], swizzled
  __shared__ __align__(16) _Float16 sV[64 * 64];   // [dim][slot], swizzled

  const int tid  = threadIdx.x;
  const int wave = tid >> 6;
  const int lane = tid & 63;
  const int l16  = lane & 15;
  const int quad = lane >> 4;
  const int hK   = (l16 >> 1) & 7;

  const int t16 = tid & 15;
  const int kg  = tid >> 4;

  const int bid  = blockIdx.x;
  const int half = bid & ((1 << ksh) - 1);
  const int qb   = bid >> ksh;
  const int b    = qb >> 4;
  const int qt   = qb & 15;
  const int q0   = qt * BQ + wave * 64;
  const int kt0  = half * ksteps;

  const float* Qb = Qg + ((size_t)b * SEQ + q0) * DIM;
  const float* Kb = Kg + (size_t)b * SEQ * DIM;
  const float* Vb = Vg + (size_t)b * SEQ * DIM;
  float*       Ob = (half ? (Opg + (size_t)(half - 1) * OELEMS) : O0g)
                    + ((size_t)b * SEQ + q0) * DIM;
  float*       Ls = lsg + (size_t)half * NROWS + b * SEQ + q0;

  // ---- Q fragments (B-operand of S^T = K*Q^T), pre-scaled ----
  half8_t qf[4][2];
  #pragma unroll
  for (int s = 0; s < 4; ++s)
    #pragma unroll
    for (int c = 0; c < 2; ++c) {
      const floatx4 f0 = *(const floatx4*)(Qb + (s * 16 + l16) * DIM + c * 32 + quad * 8);
      const floatx4 f1 = *(const floatx4*)(Qb + (s * 16 + l16) * DIM + c * 32 + quad * 8 + 4);
      half8_t h;
      #pragma unroll
      for (int j = 0; j < 4; ++j) h[j] = (_Float16)(f0[j] * QSCALE);
      #pragma unroll
      for (int j = 0; j < 4; ++j) h[4 + j] = (_Float16)(f1[j] * QSCALE);
      qf[s][c] = h;
    }

  floatx4 oacc2[4][4];   // [dim-tile n][q-slab s]
  float   lsum2[4];
  #pragma unroll
  for (int n = 0; n < 4; ++n)
    #pragma unroll
    for (int s = 0; s < 4; ++s) oacc2[n][s] = (floatx4){0.f, 0.f, 0.f, 0.f};
  #pragma unroll
  for (int s = 0; s < 4; ++s) lsum2[s] = 0.f;

  floatx4 kbuf[4], vbuf[4];

  #define LOAD_TILE(KT)                                                        \
    do {                                                                       \
      const float* Kt_ = Kb + (size_t)(KT) * BK * DIM;                         \
      const float* Vt_ = Vb + (size_t)(KT) * BK * DIM;                         \
      _Pragma("unroll")                                                        \
      for (int i = 0; i < 4; ++i) {                                            \
        const int key = kg + 16 * i;                                           \
        kbuf[i] = *(const floatx4*)(Kt_ + key * DIM + t16 * 4);                \
        vbuf[i] = *(const floatx4*)(Vt_ + key * DIM + t16 * 4);                \
      }                                                                        \
    } while (0)

  #define WRITE_TILE()                                                         \
    do {                                                                       \
      _Pragma("unroll")                                                        \
      for (int i = 0; i < 4; ++i) {                                            \
        const int key = kg + 16 * i;                                           \
        half4_t h;                                                             \
        _Pragma("unroll")                                                      \
        for (int j = 0; j < 4; ++j) h[j] = (_Float16)kbuf[i][j];               \
        *(half4_t*)&sK[swz(key, t16 * 4)] = h;                                 \
      }                                                                        \
      {                                                                        \
        const int vbase = (kg >> 2) * 8 + (kg & 3) * 2;                        \
        _Pragma("unroll")                                                      \
        for (int e = 0; e < 4; ++e) {                                          \
          const int dim = t16 * 4 + e;                                         \
          half2_t h0; h0[0] = (_Float16)vbuf[0][e]; h0[1] = (_Float16)vbuf[1][e];\
          half2_t h1; h1[0] = (_Float16)vbuf[2][e]; h1[1] = (_Float16)vbuf[3][e];\
          *(half2_t*)&sV[swz(dim, vbase)]      = h0;                           \
          *(half2_t*)&sV[swz(dim, vbase + 32)] = h1;                           \
        }                                                                      \
      }                                                                        \
    } while (0)

  #define COMPUTE_TILE()                                                       \
    do {                                                                       \
      floatx4 sc[4][4];   /* [key-tile nk][q-slab s] */                        \
      _Pragma("unroll")                                                        \
      for (int nk = 0; nk < 4; ++nk)                                           \
        _Pragma("unroll")                                                      \
        for (int s = 0; s < 4; ++s) sc[nk][s] = (floatx4){0.f, 0.f, 0.f, 0.f}; \
      _Pragma("unroll")                                                        \
      for (int nk = 0; nk < 4; ++nk)                                           \
        _Pragma("unroll")                                                      \
        for (int c = 0; c < 2; ++c) {                                          \
          half8_t kf = *(const half8_t*)&sK[(nk * 16 + l16) * 64 +             \
                                            (((c * 4 + quad) ^ hK) << 3)];     \
          _Pragma("unroll")                                                    \
          for (int s = 0; s < 4; ++s)                                          \
            sc[nk][s] = __builtin_amdgcn_mfma_f32_16x16x32_f16(kf, qf[s][c],   \
                                                               sc[nk][s], 0, 0, 0);\
        }                                                                      \
      half8_t bfrag[4][2];                                                     \
      _Pragma("unroll")                                                        \
      for (int s = 0; s < 4; ++s)                                              \
        _Pragma("unroll")                                                      \
        for (int c = 0; c < 2; ++c) {                                          \
          half8_t bf;                                                          \
          _Pragma("unroll")                                                    \
          for (int j = 0; j < 8; ++j) {                                        \
            float p = fast_exp2(sc[(c << 1) | (j & 1)][s][j >> 1]);            \
            lsum2[s] += p;                                                     \
            bf[j] = (_Float16)p;                                               \
          }                                                                    \
          bfrag[s][c] = bf;                                                    \
        }                                                                      \
      _Pragma("unroll")                                                        \
      for (int c = 0; c < 2; ++c)                                              \
        _Pragma("unroll")                                                      \
        for (int n = 0; n < 4; ++n) {                                          \
          half8_t vf = *(const half8_t*)&sV[(n * 16 + l16) * 64 +              \
                                            (((c * 4 + quad) ^ hK) << 3)];     \
          _Pragma("unroll")                                                    \
          for (int s = 0; s < 4; ++s)                                          \
            oacc2[n][s] = __builtin_amdgcn_mfma_f32_16x16x32_f16(vf, bfrag[s][c],\
                                                                 oacc2[n][s], 0, 0, 0);\
        }                                                                      \
    } while (0)

  // ---------- pipelined main loop over this block's key slice ----------
  LOAD_TILE(kt0);
  WRITE_TILE();
  __syncthreads();

  #pragma unroll 1
  for (int kt = kt0; kt < kt0 + ksteps - 1; ++kt) {
    LOAD_TILE(kt + 1);
    COMPUTE_TILE();
    __syncthreads();
    WRITE_TILE();
    __syncthreads();
  }
  COMPUTE_TILE();

  // ---------- epilogue: UNNORMALIZED partial O^T + row sums ----------
  #pragma unroll
  for (int s = 0; s < 4; ++s) {
    float v = lsum2[s];
    v += __shfl_xor(v, 16);
    v += __shfl_xor(v, 32);
    if (lane < 16) Ls[s * 16 + l16] = v;
  }
  #pragma unroll
  for (int s = 0; s < 4; ++s)
    #pragma unroll
    for (int n = 0; n < 4; ++n)
      *(floatx4*)&Ob[(s * 16 + l16) * DIM + n * 16 + quad * 4] = oacc2[n][s];

  #undef LOAD_TILE
  #undef WRITE_TILE
  #undef COMPUTE_TILE
}

// O = (sum of partials) / (sum of row sums). Partial 0 in d_out (in-place).
__global__ __launch_bounds__(256)
void attn_combine(float* __restrict__ O, const float* __restrict__ Op,
                  const float* __restrict__ lsg, int nsplit)
{
  const int i = blockIdx.x * 256 + threadIdx.x;   // float4 index
  const int row = i >> 4;
  float lsum = lsg[row];
  float4 acc = ((const float4*)O)[i];
  #pragma unroll 1
  for (int p = 1; p < nsplit; ++p) {
    lsum += lsg[(size_t)p * NROWS + row];
    const float4 bb = ((const float4*)(Op + (size_t)(p - 1) * OELEMS))[i];
    acc.x += bb.x; acc.y += bb.y; acc.z += bb.z; acc.w += bb.w;
  }
  const float inv = fast_rcp(lsum);
  acc.x *= inv; acc.y *= inv; acc.z *= inv; acc.w *= inv;
  ((float4*)O)[i] = acc;
}

extern "C" void kernel_launch(void* const* d_in, const int* in_sizes, int n_in,
                              void* d_out, int out_size, void* d_ws, size_t ws_size,
                              hipStream_t stream) {
  const float* Q = (const float*)d_in[0];
  const float* K = (const float*)d_in[1];
  const float* V = (const float*)d_in[2];
  float* O  = (float*)d_out;
  (void)in_sizes; (void)n_in; (void)out_size;

  // choose split-K from available workspace (constant across calls)
  const size_t need4 = (size_t)(3 * OELEMS + 4 * NROWS) * sizeof(float);
  int ksh, nsplit;
  if (ws_size >= need4) { ksh = 2; nsplit = 4; }
  else                  { ksh = 1; nsplit = 2; }

  float* Op = (float*)d_ws;                                  // (nsplit-1) partials
  float* Ls = (float*)d_ws + (size_t)(nsplit - 1) * OELEMS;  // nsplit row-sum sets
  const int ksteps = NKT >> ksh;

  attn_f16_flash<<<dim3((NBATCH * (SEQ / BQ)) << ksh), dim3(256), 0, stream>>>(
      Q, K, V, O, Op, Ls, ksh, ksteps);
  attn_combine<<<dim3(OELEMS / 4 / 256), dim3(256), 0, stream>>>(O, Op, Ls, nsplit);
}

// Round 10
// 166.908 us; speedup vs baseline: 4.6501x; 4.6501x over previous
//
#include <hip/hip_runtime.h>

// Transposed flash attention, f16 MFMA (16x16x32), no-max softmax, split-K=2.
// R10: K/V pre-packed ONCE into per-tile LDS-image layout (f16, swizzled,
// V transposed+slot-permuted) by a small prepack kernel. Main kernel stages
// each tile with 4 global_load_lds dwordx4 per wave (pure copy, no VGPRs, no
// cvt), LDS double-buffered -> ONE barrier per tile. Compute split into
// nk-halves: exp(h0) overlaps QK-MFMA(h1), sc liveness 64->32 regs.
// launch_bounds(256,2) only -- NEVER promise more (R9: 4 waves/EU cap=128
// regs vs ~190 live -> 1.7 GB scratch spill, 7x regression).

#define NBATCH 16
#define SEQ    4096
#define DIM    64
#define BQ     256
#define BK     64
#define NKT    (SEQ / BK)      // 64
#define KHALF  (NKT / 2)       // 32 tiles per key-half
#define OELEMS (NBATCH * SEQ * DIM)   // 4194304
#define NROWS  (NBATCH * SEQ)         // 65536
#define NTILES (NBATCH * NKT)         // 1024
#define TILEH  4096                   // halfs per 64x64 tile image (8 KB)

#define QSCALE 0.180336879f   // 0.125 * log2(e)

typedef _Float16 half2_t __attribute__((ext_vector_type(2)));
typedef _Float16 half4_t __attribute__((ext_vector_type(4)));
typedef _Float16 half8_t __attribute__((ext_vector_type(8)));
typedef float    floatx4 __attribute__((ext_vector_type(4)));

__device__ inline float fast_exp2(float x) {
#if __has_builtin(__builtin_amdgcn_exp2f)
  return __builtin_amdgcn_exp2f(x);
#else
  return exp2f(x);
#endif
}
__device__ inline float fast_rcp(float x) {
#if __has_builtin(__builtin_amdgcn_rcpf)
  return __builtin_amdgcn_rcpf(x);
#else
  return 1.0f / x;
#endif
}

// swizzled offset in halfs for element (row, col) of a 64x64 half tile
__device__ inline int swz(int row, int col) {
  return row * 64 + ((((col >> 3) ^ ((row >> 1) & 7)) << 3) | (col & 7));
}

// async 16B global->LDS copy: lds dest is wave-uniform; HW adds lane*16
__device__ inline void async16(const void* g, void* l) {
  __builtin_amdgcn_global_load_lds(
      (const __attribute__((address_space(1))) void*)g,
      (__attribute__((address_space(3))) void*)l, 16, 0, 0);
}

// ---------------- prepack: K,V f32 -> per-tile f16 LDS images ----------------
// One block per (b, kt) tile. Reuses R8's verified staging/swizzle logic,
// then dumps the LDS image flat to global.
__global__ __launch_bounds__(256, 2)
void prepack_kv(const float* __restrict__ Kg, const float* __restrict__ Vg,
                _Float16* __restrict__ Kh, _Float16* __restrict__ Vh)
{
  __shared__ __align__(16) _Float16 sKi[TILEH];
  __shared__ __align__(16) _Float16 sVi[TILEH];
  const int tid = threadIdx.x;
  const int t16 = tid & 15;
  const int kg  = tid >> 4;
  const int bt  = blockIdx.x;                 // b*64 + kt
  const float* Kt_ = Kg + (size_t)bt * BK * DIM;
  const float* Vt_ = Vg + (size_t)bt * BK * DIM;

  floatx4 kbuf[4], vbuf[4];
  #pragma unroll
  for (int i = 0; i < 4; ++i) {
    const int key = kg + 16 * i;
    kbuf[i] = *(const floatx4*)(Kt_ + key * DIM + t16 * 4);
    vbuf[i] = *(const floatx4*)(Vt_ + key * DIM + t16 * 4);
  }
  #pragma unroll
  for (int i = 0; i < 4; ++i) {               // K: [key][dim] swizzled
    const int key = kg + 16 * i;
    half4_t h;
    #pragma unroll
    for (int j = 0; j < 4; ++j) h[j] = (_Float16)kbuf[i][j];
    *(half4_t*)&sKi[swz(key, t16 * 4)] = h;
  }
  {                                           // V: [dim][slot] swizzled
    const int vbase = (kg >> 2) * 8 + (kg & 3) * 2;
    #pragma unroll
    for (int e = 0; e < 4; ++e) {
      const int dim = t16 * 4 + e;
      half2_t h0; h0[0] = (_Float16)vbuf[0][e]; h0[1] = (_Float16)vbuf[1][e];
      half2_t h1; h1[0] = (_Float16)vbuf[2][e]; h1[1] = (_Float16)vbuf[3][e];
      *(half2_t*)&sVi[swz(dim, vbase)]      = h0;
      *(half2_t*)&sVi[swz(dim, vbase + 32)] = h1;
    }
  }
  __syncthreads();
  half8_t* Ko = (half8_t*)(Kh + (size_t)bt * TILEH);
  half8_t* Vo = (half8_t*)(Vh + (size_t)bt * TILEH);
  const half8_t* Ks = (const half8_t*)sKi;
  const half8_t* Vs = (const half8_t*)sVi;
  Ko[tid] = Ks[tid]; Ko[tid + 256] = Ks[tid + 256];
  Vo[tid] = Vs[tid]; Vo[tid + 256] = Vs[tid + 256];
}

// ---------------- main kernel ----------------
__global__ __launch_bounds__(256, 2)
void attn_f16_flash(const float* __restrict__ Qg, const _Float16* __restrict__ Kh,
                    const _Float16* __restrict__ Vh, float* __restrict__ O0g,
                    float* __restrict__ O1g, float* __restrict__ lsg)
{
  __shared__ __align__(16) _Float16 sT[2][2 * TILEH];  // [buf][ K | V ]

  const int tid  = threadIdx.x;
  const int wave = tid >> 6;
  const int lane = tid & 63;
  const int l16  = lane & 15;
  const int quad = lane >> 4;
  const int hK   = (l16 >> 1) & 7;

  const int bid  = blockIdx.x;
  const int half = bid & 1;
  const int qb   = bid >> 1;
  const int b    = qb >> 4;
  const int qt   = qb & 15;
  const int q0   = qt * BQ + wave * 64;
  const int kt0  = half * KHALF;

  const float* Qb = Qg + ((size_t)b * SEQ + q0) * DIM;
  float*       Ob = (half ? O1g : O0g) + ((size_t)b * SEQ + q0) * DIM;
  float*       Ls = lsg + (size_t)half * NROWS + b * SEQ + q0;

  // ---- Q fragments (B-operand of S^T = K*Q^T), pre-scaled ----
  half8_t qf[4][2];
  #pragma unroll
  for (int s = 0; s < 4; ++s)
    #pragma unroll
    for (int c = 0; c < 2; ++c) {
      const floatx4 f0 = *(const floatx4*)(Qb + (s * 16 + l16) * DIM + c * 32 + quad * 8);
      const floatx4 f1 = *(const floatx4*)(Qb + (s * 16 + l16) * DIM + c * 32 + quad * 8 + 4);
      half8_t h;
      #pragma unroll
      for (int j = 0; j < 4; ++j) h[j] = (_Float16)(f0[j] * QSCALE);
      #pragma unroll
      for (int j = 0; j < 4; ++j) h[4 + j] = (_Float16)(f1[j] * QSCALE);
      qf[s][c] = h;
    }

  floatx4 oacc2[4][4];   // [dim-tile n][q-slab s]
  float   lsum2[4];
  #pragma unroll
  for (int n = 0; n < 4; ++n)
    #pragma unroll
    for (int s = 0; s < 4; ++s) oacc2[n][s] = (floatx4){0.f, 0.f, 0.f, 0.f};
  #pragma unroll
  for (int s = 0; s < 4; ++s) lsum2[s] = 0.f;

  // ---- async staging: 4 x 16B-per-lane copies per wave per tile ----
  #define ASYNC(KT, BUF)                                                       \
    do {                                                                       \
      const char* gk = (const char*)(Kh + ((size_t)b * NKT + (KT)) * TILEH)    \
                       + wave * 2048;                                          \
      const char* gv = (const char*)(Vh + ((size_t)b * NKT + (KT)) * TILEH)    \
                       + wave * 2048;                                          \
      char* lk = (char*)(&sT[BUF][0])     + wave * 2048;                       \
      char* lv = (char*)(&sT[BUF][TILEH]) + wave * 2048;                       \
      async16(gk + lane * 16,        lk);                                      \
      async16(gk + 1024 + lane * 16, lk + 1024);                               \
      async16(gv + lane * 16,        lv);                                      \
      async16(gv + 1024 + lane * 16, lv + 1024);                               \
    } while (0)

  // ---- compute one 64-key tile from buffer BUF, split into nk-halves ----
  #define COMPUTE(BUF)                                                         \
    do {                                                                       \
      const _Float16* SKB = &sT[BUF][0];                                       \
      const _Float16* SVB = &sT[BUF][TILEH];                                   \
      _Pragma("unroll")                                                        \
      for (int h = 0; h < 2; ++h) {                                            \
        floatx4 sc2[2][4];                                                     \
        _Pragma("unroll")                                                      \
        for (int k2 = 0; k2 < 2; ++k2)                                         \
          _Pragma("unroll")                                                    \
          for (int s = 0; s < 4; ++s) sc2[k2][s] = (floatx4){0.f, 0.f, 0.f, 0.f};\
        _Pragma("unroll")                                                      \
        for (int k2 = 0; k2 < 2; ++k2) {                                       \
          const int nk = h * 2 + k2;                                           \
          _Pragma("unroll")                                                    \
          for (int c = 0; c < 2; ++c) {                                        \
            half8_t kf = *(const half8_t*)&SKB[(nk * 16 + l16) * 64 +          \
                                               (((c * 4 + quad) ^ hK) << 3)];  \
            _Pragma("unroll")                                                  \
            for (int s = 0; s < 4; ++s)                                        \
              sc2[k2][s] = __builtin_amdgcn_mfma_f32_16x16x32_f16(             \
                  kf, qf[s][c], sc2[k2][s], 0, 0, 0);                          \
          }                                                                    \
        }                                                                      \
        half8_t bfr[4];                                                        \
        _Pragma("unroll")                                                      \
        for (int s = 0; s < 4; ++s) {                                          \
          half8_t bf;                                                          \
          _Pragma("unroll")                                                    \
          for (int j = 0; j < 8; ++j) {                                        \
            float p = fast_exp2(sc2[j & 1][s][j >> 1]);                        \
            lsum2[s] += p;                                                     \
            bf[j] = (_Float16)p;                                               \
          }                                                                    \
          bfr[s] = bf;                                                         \
        }                                                                      \
        _Pragma("unroll")                                                      \
        for (int n = 0; n < 4; ++n) {                                          \
          half8_t vf = *(const half8_t*)&SVB[(n * 16 + l16) * 64 +             \
                                             (((h * 4 + quad) ^ hK) << 3)];    \
          _Pragma("unroll")                                                    \
          for (int s = 0; s < 4; ++s)                                          \
            oacc2[n][s] = __builtin_amdgcn_mfma_f32_16x16x32_f16(              \
                vf, bfr[s], oacc2[n][s], 0, 0, 0);                             \
        }                                                                      \
      }                                                                        \
    } while (0)

  // ---------- double-buffered main loop: ONE barrier per tile ----------
  ASYNC(kt0, 0);
  __syncthreads();                       // vmcnt(0) drained by compiler

  #pragma unroll 1
  for (int t = 0; t < (KHALF - 2) / 2; ++t) {   // 15 pairs -> tiles 0..29
    ASYNC(kt0 + 2 * t + 1, 1);
    COMPUTE(0);
    __syncthreads();
    ASYNC(kt0 + 2 * t + 2, 0);
    COMPUTE(1);
    __syncthreads();
  }
  ASYNC(kt0 + KHALF - 1, 1);             // tile 31 load
  COMPUTE(0);                            // tile 30
  __syncthreads();
  COMPUTE(1);                            // tile 31

  // ---------- epilogue: UNNORMALIZED partial O^T + row sums ----------
  #pragma unroll
  for (int s = 0; s < 4; ++s) {
    float v = lsum2[s];
    v += __shfl_xor(v, 16);
    v += __shfl_xor(v, 32);
    if (lane < 16) Ls[s * 16 + l16] = v;
  }
  #pragma unroll
  for (int s = 0; s < 4; ++s)
    #pragma unroll
    for (int n = 0; n < 4; ++n)
      *(floatx4*)&Ob[(s * 16 + l16) * DIM + n * 16 + quad * 4] = oacc2[n][s];

  #undef ASYNC
  #undef COMPUTE
}

// O = (O0 + O1) / (l0 + l1); O0 in d_out (in-place), O1/l0/l1 in ws.
__global__ __launch_bounds__(256)
void attn_combine(float* __restrict__ O, const float* __restrict__ O1,
                  const float* __restrict__ lsg)
{
  const int i = blockIdx.x * 256 + threadIdx.x;   // float4 index
  const int row = i >> 4;
  const float inv = fast_rcp(lsg[row] + lsg[NROWS + row]);
  const float4 a  = ((const float4*)O)[i];
  const float4 bb = ((const float4*)O1)[i];
  float4 r;
  r.x = (a.x + bb.x) * inv;
  r.y = (a.y + bb.y) * inv;
  r.z = (a.z + bb.z) * inv;
  r.w = (a.w + bb.w) * inv;
  ((float4*)O)[i] = r;
}

extern "C" void kernel_launch(void* const* d_in, const int* in_sizes, int n_in,
                              void* d_out, int out_size, void* d_ws, size_t ws_size,
                              hipStream_t stream) {
  const float* Q = (const float*)d_in[0];
  const float* K = (const float*)d_in[1];
  const float* V = (const float*)d_in[2];
  float* O  = (float*)d_out;
  (void)in_sizes; (void)n_in; (void)out_size; (void)ws_size;

  // ws layout (floats): O1 [OELEMS] | Ls [2*NROWS] | Kh,Vh images (f16)
  float*     O1 = (float*)d_ws;
  float*     Ls = O1 + OELEMS;
  _Float16*  Kh = (_Float16*)(Ls + 2 * NROWS);
  _Float16*  Vh = Kh + (size_t)NTILES * TILEH;
  // total: (4.19M + 0.13M)*4B + 2*4.19M*2B = ~34.1 MB (fits: R9 proved >=51 MB)

  prepack_kv<<<dim3(NTILES), dim3(256), 0, stream>>>(K, V, Kh, Vh);
  attn_f16_flash<<<dim3(2 * NBATCH * (SEQ / BQ)), dim3(256), 0, stream>>>(
      Q, Kh, Vh, O, O1, Ls);
  attn_combine<<<dim3(OELEMS / 4 / 256), dim3(256), 0, stream>>>(O, O1, Ls);
}